// Round 14
// baseline (324.733 us; speedup 1.0000x reference)
//
#include <hip/hip_runtime.h>

typedef unsigned short u16;
typedef __attribute__((ext_vector_type(8))) short short8;
typedef __attribute__((ext_vector_type(4))) float f32x4;
typedef __attribute__((ext_vector_type(16))) float f32x16;
typedef __attribute__((ext_vector_type(4))) unsigned u32x4;

struct __align__(8) us4 { u16 x, y, z, w; };
struct __align__(8) ui2 { unsigned x, y; };

// log2(e) / (sqrt(64) + 1e-6)  -- folded into W_q at prep time
#define CEXP (1.44269504089f / (8.0f + 1e-6f))

// ---------- helpers ----------
__device__ __forceinline__ u16 f2bf(float f) {
  unsigned u = __builtin_bit_cast(unsigned, f);
  unsigned r = (u + 0x7FFFu + ((u >> 16) & 1u)) >> 16;  // RNE
  return (u16)r;
}

// truncation pack: {bf16(b)[hi16] , bf16(a)[lo16]} in ONE v_perm_b32
__device__ __forceinline__ unsigned pack_bf2_trunc(float a, float b) {
  return __builtin_amdgcn_perm(__builtin_bit_cast(unsigned, b),
                               __builtin_bit_cast(unsigned, a), 0x07060302u);
}

__device__ __forceinline__ void async_load16(const void* g, void* l) {
  __builtin_amdgcn_global_load_lds((const __attribute__((address_space(1))) void*)g,
                                   (__attribute__((address_space(3))) void*)l, 16, 0, 0);
}

// ---------- weight prep ----------
// wqkvT: [1536,512] bf16 (rows 0-511 = Wq^T*CEXP, 512-1023 = Wk^T, 1024-1535 = Wv^T)
__global__ void prep_weights(const float* __restrict__ Wq, const float* __restrict__ Wk,
                             const float* __restrict__ Wv, const float* __restrict__ Wo,
                             const float* __restrict__ w1, const float* __restrict__ w2,
                             u16* __restrict__ wqkvT, u16* __restrict__ woT,
                             u16* __restrict__ w1b, u16* __restrict__ w2b) {
  const int z = blockIdx.y;
  const int stride = gridDim.x * blockDim.x;
  const int i0 = blockIdx.x * blockDim.x + threadIdx.x;
  if (z < 4) {
    const float* src = z == 0 ? Wq : z == 1 ? Wk : z == 2 ? Wv : Wo;
    u16* dst = z < 3 ? wqkvT + z * 512 * 512 : woT;
    const float scale = (z == 0) ? CEXP : 1.0f;
    for (int i = i0; i < 512 * 512; i += stride) {
      int n = i >> 9, k = i & 511;
      dst[i] = f2bf(src[k * 512 + n] * scale);   // out[n*512+k] = in[k,n]
    }
  } else {
    const float* src = z == 4 ? w1 : w2;
    u16* dst = z == 4 ? w1b : w2b;
    for (int i = i0; i < 2048 * 512; i += stride) dst[i] = f2bf(src[i]);
  }
}

// ---------- LayerNorm row kernel (+ optional bf16 cast of K,V rows) ----------
template <bool KV>
__launch_bounds__(128)
__global__ void ln_cast(const float* __restrict__ X, const float* __restrict__ gw,
                        const float* __restrict__ bw, u16* __restrict__ Y,
                        const float* __restrict__ Kin, const float* __restrict__ Vin,
                        u16* __restrict__ Kb, u16* __restrict__ Vb) {
  const int row = blockIdx.x, t = threadIdx.x;
  const size_t base = (size_t)row * 512;
  float4 x = ((const float4*)(X + base))[t];
  float s = x.x + x.y + x.z + x.w;
  float ss = x.x * x.x + x.y * x.y + x.z * x.z + x.w * x.w;
#pragma unroll
  for (int off = 32; off > 0; off >>= 1) {
    s += __shfl_xor(s, off);
    ss += __shfl_xor(ss, off);
  }
  __shared__ float red[4];
  if ((t & 63) == 0) { red[(t >> 6) * 2] = s; red[(t >> 6) * 2 + 1] = ss; }
  __syncthreads();
  const float tot = red[0] + red[2], tss = red[1] + red[3];
  const float mu = tot * (1.0f / 512.0f);
  const float var = tss * (1.0f / 512.0f) - mu * mu;
  const float rs = rsqrtf(var + 1e-5f);
  float4 g4 = ((const float4*)gw)[t];
  float4 b4 = ((const float4*)bw)[t];
  us4 o;
  o.x = f2bf((x.x - mu) * rs * g4.x + b4.x);
  o.y = f2bf((x.y - mu) * rs * g4.y + b4.y);
  o.z = f2bf((x.z - mu) * rs * g4.z + b4.z);
  o.w = f2bf((x.w - mu) * rs * g4.w + b4.w);
  ((us4*)(Y + base))[t] = o;
  if constexpr (KV) {
    float4 k4 = ((const float4*)(Kin + base))[t];
    float4 v4 = ((const float4*)(Vin + base))[t];
    us4 ko, vo;
    ko.x = f2bf(k4.x); ko.y = f2bf(k4.y); ko.z = f2bf(k4.z); ko.w = f2bf(k4.w);
    vo.x = f2bf(v4.x); vo.y = f2bf(v4.y); vo.z = f2bf(v4.z); vo.w = f2bf(v4.w);
    ((us4*)(Kb + base))[t] = ko;
    ((us4*)(Vb + base))[t] = vo;
  }
}

// ---------- merged QKV projection GEMM (XOR-swizzled LDS chunks) ----------
// BK=64 per barrier pair as TWO independent 32-K sub-tiles. 4 blocks/CU (32KB LDS).
// K output (sel==1) FRAGMENT-ORDERED (QK A-operand):
//   kfrag[((bh*128 + key/32)*4 + ks)*64 + (key&31) + 32*hik]*8 + e, d = ks*16+hik*8+e
// V output (sel==2) FRAGMENT-ORDERED (PV A-operand):
//   vfrag[((bh*128 + key/32)*4 + kstep*2 + vb)*64 + (dv&31) + 32*((key>>3)&1)]*8 + (key&7)
//   where kstep = (key>>4)&1, vb = dv>>5.  One wave's fragment = 16B/lane coalesced.
__launch_bounds__(256, 4)
__global__ void gemm_qkv(const u16* __restrict__ Aq, const u16* __restrict__ Ak,
                         const u16* __restrict__ Av, const u16* __restrict__ Bt,
                         u16* __restrict__ qb, u16* __restrict__ kb, u16* __restrict__ vtb) {
  __shared__ __align__(16) u16 sA[2][128 * 32];
  __shared__ __align__(16) u16 sB[2][128 * 32];
  const int tid = threadIdx.x;
  const int wave = tid >> 6, lane = tid & 63;
  const int l15 = lane & 15, quad = lane >> 4;
  const int qsw = (quad ^ ((l15 >> 1) & 3)) * 8;
  const int m0 = blockIdx.x * 128, n0 = blockIdx.y * 128;
  const int sel = n0 >> 9;  // 0=q, 1=k, 2=v
  const u16* A = sel == 0 ? Aq : sel == 1 ? Ak : Av;
  const int wm = (wave >> 1) * 64, wn = (wave & 1) * 64;
  const int u0 = wave * 64 + lane, u1 = u0 + 256;
  const int sw0 = ((u0 & 3) ^ ((u0 >> 3) & 3)) * 8;  // same value for u1
  const int K = 512;

  const u16* a0 = A + (size_t)(m0 + (u0 >> 2)) * K + sw0;
  const u16* a1 = A + (size_t)(m0 + (u1 >> 2)) * K + sw0;
  const u16* b0 = Bt + (size_t)(n0 + (u0 >> 2)) * K + sw0;
  const u16* b1p = Bt + (size_t)(n0 + (u1 >> 2)) * K + sw0;

  f32x4 acc[4][4] = {};
  for (int k0 = 0; k0 < K; k0 += 64) {
#pragma unroll
    for (int hf = 0; hf < 2; hf++) {
      const int kk = k0 + hf * 32;
      async_load16(a0 + kk, &sA[hf][wave * 512]);
      async_load16(a1 + kk, &sA[hf][2048 + wave * 512]);
      async_load16(b0 + kk, &sB[hf][wave * 512]);
      async_load16(b1p + kk, &sB[hf][2048 + wave * 512]);
    }
    __syncthreads();
#pragma unroll
    for (int hf = 0; hf < 2; hf++) {
      short8 af[4], bfr[4];
#pragma unroll
      for (int i = 0; i < 4; i++)
        af[i] = *(const short8*)&sA[hf][(wm + i * 16 + l15) * 32 + qsw];
#pragma unroll
      for (int j = 0; j < 4; j++)
        bfr[j] = *(const short8*)&sB[hf][(wn + j * 16 + l15) * 32 + qsw];
#pragma unroll
      for (int i = 0; i < 4; i++)
#pragma unroll
        for (int j = 0; j < 4; j++)
          acc[i][j] = __builtin_amdgcn_mfma_f32_16x16x32_bf16(af[i], bfr[j], acc[i][j], 0, 0, 0);
    }
    __syncthreads();
  }

#pragma unroll
  for (int i = 0; i < 4; i++) {
#pragma unroll
    for (int j = 0; j < 4; j++) {
      const int ocol = ((n0 + wn) & 511) + j * 16 + l15;
      const int row0 = m0 + wm + i * 16 + quad * 4;
      if (sel == 0) {
#pragma unroll
        for (int r = 0; r < 4; r++) qb[(size_t)(row0 + r) * 512 + ocol] = f2bf(acc[i][j][r]);
      } else if (sel == 1) {
        // fragment-ordered K (see header comment)
        const int d = ocol & 63, hh2 = ocol >> 6;
        const int ks = d >> 4, hik = (d >> 3) & 1, e = d & 7;
#pragma unroll
        for (int r = 0; r < 4; r++) {
          const int row = row0 + r;
          const int bb = row >> 12, keys = row & 4095;
          const size_t addr =
              (((size_t)((bb * 8 + hh2) * 128 + (keys >> 5)) * 4 + ks) * 64 +
               (keys & 31) + 32 * hik) * 8 + e;
          kb[addr] = f2bf(acc[i][j][r]);
        }
      } else {
        // fragment-ordered V (see header comment); r spans 4 consecutive keys that
        // stay within one lane's 8-elem group -> one us4 store.
        const int dv = ocol & 63, hh2 = ocol >> 6;
        const int bb = row0 >> 12, key = row0 & 4095;
        const size_t base =
            (((size_t)((bb * 8 + hh2) * 128 + (key >> 5)) * 4 + ((key >> 4) & 1) * 2 +
              (dv >> 5)) * 64 + (dv & 31) + 32 * ((key >> 3) & 1)) * 8 + (key & 7);
        us4 pk;
        pk.x = f2bf(acc[i][j][0]); pk.y = f2bf(acc[i][j][1]);
        pk.z = f2bf(acc[i][j][2]); pk.w = f2bf(acc[i][j][3]);
        *(us4*)&vtb[base] = pk;
      }
    }
  }
}

// ---------- GEMM: C[M,N] = A[M,K] @ Bt[N,K]^T (XOR-swizzled LDS chunks) ----------
// BK=64 per barrier pair as TWO independent 32-K sub-tiles. LB=4 -> 4 blocks/CU.
// EP: 2 = fp32 store + res add | 3 = +bias, exact GELU, bf16 | 4 = +bias +res, fp32
template <int EP, int TN, int LB>
__launch_bounds__(256, LB)
__global__ void gemm_bt(const u16* __restrict__ A, const u16* __restrict__ Bt,
                        int M, int N, int K, void* __restrict__ Cp,
                        const float* __restrict__ bias, const float* __restrict__ res) {
  constexpr int MI = (TN == 128) ? 4 : 2;
  __shared__ __align__(16) u16 sA[2][128 * 32];
  __shared__ __align__(16) u16 sB[2][TN * 32];
  const int tid = threadIdx.x;
  const int wave = tid >> 6, lane = tid & 63;
  const int l15 = lane & 15, quad = lane >> 4;
  const int qsw = (quad ^ ((l15 >> 1) & 3)) * 8;
  const int m0 = blockIdx.x * 128, n0 = blockIdx.y * TN;
  const int wm = (TN == 128) ? (wave >> 1) * 64 : wave * 32;
  const int wn = (TN == 128) ? (wave & 1) * 64 : 0;
  const int u0 = wave * 64 + lane, u1 = u0 + 256;
  const int sw0 = ((u0 & 3) ^ ((u0 >> 3) & 3)) * 8;

  const u16* a0 = A + (size_t)(m0 + (u0 >> 2)) * K + sw0;
  const u16* a1 = A + (size_t)(m0 + (u1 >> 2)) * K + sw0;
  const u16* b0 = Bt + (size_t)(n0 + (u0 >> 2)) * K + sw0;

  f32x4 acc[MI][4] = {};
  for (int k0 = 0; k0 < K; k0 += 64) {
#pragma unroll
    for (int hf = 0; hf < 2; hf++) {
      const int kk = k0 + hf * 32;
      async_load16(a0 + kk, &sA[hf][wave * 512]);
      async_load16(a1 + kk, &sA[hf][2048 + wave * 512]);
      async_load16(b0 + kk, &sB[hf][wave * 512]);
      if constexpr (TN == 128) {
        const u16* b1p = Bt + (size_t)(n0 + (u1 >> 2)) * K + sw0;
        async_load16(b1p + kk, &sB[hf][2048 + wave * 512]);
      }
    }
    __syncthreads();
#pragma unroll
    for (int hf = 0; hf < 2; hf++) {
      short8 af[MI], bfr[4];
#pragma unroll
      for (int i = 0; i < MI; i++)
        af[i] = *(const short8*)&sA[hf][(wm + i * 16 + l15) * 32 + qsw];
#pragma unroll
      for (int j = 0; j < 4; j++)
        bfr[j] = *(const short8*)&sB[hf][(wn + j * 16 + l15) * 32 + qsw];
#pragma unroll
      for (int i = 0; i < MI; i++)
#pragma unroll
        for (int j = 0; j < 4; j++)
          acc[i][j] = __builtin_amdgcn_mfma_f32_16x16x32_bf16(af[i], bfr[j], acc[i][j], 0, 0, 0);
    }
    __syncthreads();
  }

#pragma unroll
  for (int i = 0; i < MI; i++) {
#pragma unroll
    for (int j = 0; j < 4; j++) {
      const int col = n0 + wn + j * 16 + l15;
      const int row0 = m0 + wm + i * 16 + quad * 4;
      if (EP == 2) {
        float* C = (float*)Cp;
#pragma unroll
        for (int r = 0; r < 4; r++) {
          size_t idx = (size_t)(row0 + r) * N + col;
          C[idx] = acc[i][j][r] + res[idx];
        }
      } else if (EP == 3) {
        u16* C = (u16*)Cp;
        const float bv = bias[col];
#pragma unroll
        for (int r = 0; r < 4; r++) {
          float xx = acc[i][j][r] + bv;
          float gl = 0.5f * xx * (1.0f + erff(xx * 0.70710678118f));
          C[(size_t)(row0 + r) * N + col] = f2bf(gl);
        }
      } else {
        float* C = (float*)Cp;
        const float bv = bias[col];
#pragma unroll
        for (int r = 0; r < 4; r++) {
          size_t idx = (size_t)(row0 + r) * N + col;
          C[idx] = acc[i][j][r] + bv + res[idx];
        }
      }
    }
  }
}

// ---------- flash attention: BARRIER-FREE, K and V both from L2 as fragments ----------
// 8 waves x 512 threads = 4 q-groups (32 q each) x 2 key-halves; q-tile 128.
// grid (16 bh, 32 qt) = 512 blocks = 2/CU; 4 waves/SIMD (regs ~110 <= 128).
// Main loop has ZERO LDS and ZERO barriers. gemm_qkv writes both K and V
// fragment-ordered; each wave free-runs its 64 tiles: QK from kc regs, reload kc(t+1)
// right after use (in flight under exp/pack/PV ~400cyc > L2 lat), exp/pack in-register,
// PV from vc regs, reload vc(t+1) after use (in flight under next QK+exp+pack).
// Waves desync -> MFMA/VALU/L2 overlap across 16 waves/CU (the per-tile barrier made
// all waves burst the same pipe in lockstep: sum-of-pipes ~= wall for rounds 8-12).
// Same-kh waves read identical fragments within ~1 tile drift -> L1 absorbs 4x reuse.
// LDS (33.8 KB) only for the final 2-way key-split merge.
__launch_bounds__(512, 2)
__global__ void attn_kernel(const u16* __restrict__ qb, const u16* __restrict__ kfrag,
                            const u16* __restrict__ vfrag, u16* __restrict__ ctx) {
  __shared__ __align__(16) u16 smem[16896];  // merge scratch only
  const int tid = threadIdx.x;
  const int wave = tid >> 6, lane = tid & 63;
  const int l31 = lane & 31, hi = lane >> 5;
  const int qg = wave >> 1, kh = wave & 1;
  const int bh = blockIdx.x, b = bh >> 3, h = bh & 7;
  const int q0 = blockIdx.y * 128;
  const size_t rb = (size_t)b * 4096;
  const int qrow = q0 + qg * 32 + l31;

  // Q B-fragment: qf[ks] elem e -> Q[qrow][h*64 + ks*16 + hi*8 + e]
  short8 qf[4];
#pragma unroll
  for (int ks = 0; ks < 4; ks++)
    qf[ks] = *(const short8*)&qb[(rb + qrow) * 512 + h * 64 + ks * 16 + hi * 8];

  // fragment pointers: tile t -> key32 = 2t + kh; both advance 4096 u16/tile.
  const u16* kp = kfrag + ((size_t)(bh * 128 + kh) * 4) * 512 + lane * 8;
  const u16* vp = vfrag + ((size_t)(bh * 128 + kh) * 4) * 512 + lane * 8;

  short8 kc[4], vc[4];
  f32x16 ov[2] = {};
  float l_part = 0.f;

  // prologue: tile-0 fragments
#pragma unroll
  for (int ks = 0; ks < 4; ks++) kc[ks] = *(const short8*)(kp + ks * 512);
  kp += 4096;
#pragma unroll
  for (int f = 0; f < 4; f++) vc[f] = *(const short8*)(vp + f * 512);
  vp += 4096;

  for (int t = 0; t < 64; t++) {
    // ---- QK(t) ----
    f32x16 st = {};
    __builtin_amdgcn_s_setprio(1);
#pragma unroll
    for (int ks = 0; ks < 4; ks++)
      st = __builtin_amdgcn_mfma_f32_32x32x16_bf16(kc[ks], qf[ks], st, 0, 0, 0);
    __builtin_amdgcn_s_setprio(0);
    // reload kc for t+1 (covered by exp/pack/PV below)
    if (t < 63) {
#pragma unroll
      for (int ks = 0; ks < 4; ks++) kc[ks] = *(const short8*)(kp + ks * 512);
      kp += 4096;
    }
    // ---- exp + denominator partial ----
    float p[16];
#pragma unroll
    for (int i = 0; i < 16; i++) p[i] = __builtin_amdgcn_exp2f(st[i]);
#pragma unroll
    for (int i = 0; i < 16; i += 4)
      l_part += (p[i] + p[i + 1]) + (p[i + 2] + p[i + 3]);
    // ---- pack to bf16, build PV B-fragments in-register ----
    // lane (q=l31, hi) holds keys (reg&3)+8*(reg>>2)+4*hi of its 32-key block.
    unsigned x0 = pack_bf2_trunc(p[0], p[1]), x1 = pack_bf2_trunc(p[2], p[3]);
    unsigned x2 = pack_bf2_trunc(p[4], p[5]), x3 = pack_bf2_trunc(p[6], p[7]);
    unsigned x4 = pack_bf2_trunc(p[8], p[9]), x5 = pack_bf2_trunc(p[10], p[11]);
    unsigned x6 = pack_bf2_trunc(p[12], p[13]), x7 = pack_bf2_trunc(p[14], p[15]);
    auto r0 = __builtin_amdgcn_permlane32_swap(x0, x2, false, false);
    auto r1 = __builtin_amdgcn_permlane32_swap(x1, x3, false, false);
    auto r2 = __builtin_amdgcn_permlane32_swap(x4, x6, false, false);
    auto r3 = __builtin_amdgcn_permlane32_swap(x5, x7, false, false);
    u32x4 w0 = {r0[0], r1[0], r0[1], r1[1]};  // kstep 0: keys hi*8 + 0..7
    u32x4 w1 = {r2[0], r3[0], r2[1], r3[1]};  // kstep 1: keys 16 + hi*8 + 0..7
    short8 pf0 = __builtin_bit_cast(short8, w0);
    short8 pf1 = __builtin_bit_cast(short8, w1);
    // ---- PV(t): vc[kstep*2+vb] ----
    __builtin_amdgcn_s_setprio(1);
    ov[0] = __builtin_amdgcn_mfma_f32_32x32x16_bf16(vc[0], pf0, ov[0], 0, 0, 0);
    ov[1] = __builtin_amdgcn_mfma_f32_32x32x16_bf16(vc[1], pf0, ov[1], 0, 0, 0);
    ov[0] = __builtin_amdgcn_mfma_f32_32x32x16_bf16(vc[2], pf1, ov[0], 0, 0, 0);
    ov[1] = __builtin_amdgcn_mfma_f32_32x32x16_bf16(vc[3], pf1, ov[1], 0, 0, 0);
    __builtin_amdgcn_s_setprio(0);
    // reload vc for t+1 (covered by next QK/exp/pack)
    if (t < 63) {
#pragma unroll
      for (int f = 0; f < 4; f++) vc[f] = *(const short8*)(vp + f * 512);
      vp += 4096;
    }
  }

  // ---- 2-way key-split merge through LDS ----
  float l2 = l_part + __shfl_xor(l_part, 32);
  __syncthreads();
  float* mrg = (float*)smem;           // (qg*32 + vb*16 + e)*64 + lane : 32 KB
  float* mrgl = (float*)smem + 8192;   // qg*64 + lane : 1 KB
  if (kh == 1) {
#pragma unroll
    for (int vb = 0; vb < 2; vb++)
#pragma unroll
      for (int e = 0; e < 16; e++)
        mrg[(qg * 32 + vb * 16 + e) * 64 + lane] = ov[vb][e];
    mrgl[qg * 64 + lane] = l2;
  }
  __syncthreads();
  if (kh == 0) {
    const float inv = 1.0f / (l2 + mrgl[qg * 64 + lane]);
#pragma unroll
    for (int vb = 0; vb < 2; vb++) {
#pragma unroll
      for (int rg = 0; rg < 4; rg++) {
        us4 o;
        o.x = f2bf((ov[vb][rg * 4 + 0] + mrg[(qg * 32 + vb * 16 + rg * 4 + 0) * 64 + lane]) * inv);
        o.y = f2bf((ov[vb][rg * 4 + 1] + mrg[(qg * 32 + vb * 16 + rg * 4 + 1) * 64 + lane]) * inv);
        o.z = f2bf((ov[vb][rg * 4 + 2] + mrg[(qg * 32 + vb * 16 + rg * 4 + 2) * 64 + lane]) * inv);
        o.w = f2bf((ov[vb][rg * 4 + 3] + mrg[(qg * 32 + vb * 16 + rg * 4 + 3) * 64 + lane]) * inv);
        *(us4*)&ctx[(rb + qrow) * 512 + h * 64 + vb * 32 + rg * 8 + hi * 4] = o;
      }
    }
  }
}

// ---------- launch ----------
extern "C" void kernel_launch(void* const* d_in, const int* in_sizes, int n_in,
                              void* d_out, int out_size, void* d_ws, size_t ws_size,
                              hipStream_t stream) {
  (void)in_sizes; (void)n_in; (void)out_size; (void)ws_size;
  const float* Q = (const float*)d_in[0];
  const float* K = (const float*)d_in[1];
  const float* V = (const float*)d_in[2];
  const float* W_q = (const float*)d_in[3];
  const float* W_k = (const float*)d_in[4];
  const float* W_v = (const float*)d_in[5];
  const float* W_o = (const float*)d_in[6];
  const float* ln1_g = (const float*)d_in[7];
  const float* ln1_b = (const float*)d_in[8];
  const float* ln2_g = (const float*)d_in[9];
  const float* ln2_b = (const float*)d_in[10];
  const float* w1 = (const float*)d_in[11];
  const float* b1 = (const float*)d_in[12];
  const float* w2 = (const float*)d_in[13];
  const float* b2 = (const float*)d_in[14];

  char* w = (char*)d_ws;
  const size_t MB = 1u << 20;
  u16* wqkvT = (u16*)(w);                       // 1.5 MB [1536,512]
  u16* woT = (u16*)(w + 3 * MB / 2);            // 0.5 MB
  u16* w1b = (u16*)(w + 2 * MB);                // 2 MB
  u16* w2b = (u16*)(w + 4 * MB);                // 2 MB
  u16* Qn  = (u16*)(w + 6 * MB);                // 8 MB
  u16* Kb  = (u16*)(w + 14 * MB);               // 8 MB
  u16* Vb  = (u16*)(w + 22 * MB);               // 8 MB
  u16* qb  = (u16*)(w + 30 * MB);               // 8 MB
  u16* kb  = (u16*)(w + 38 * MB);               // 8 MB (fragment-ordered K)
  u16* vtb = (u16*)(w + 46 * MB);               // 8 MB (fragment-ordered V)
  u16* ctx = (u16*)(w + 54 * MB);               // 8 MB
  float* X = (float*)(w + 62 * MB);             // 16 MB
  u16* Xn  = (u16*)(w + 6 * MB);                // reuse Qn
  u16* hb  = (u16*)(w + 14 * MB);               // reuse Kb/Vb/qb, 32 MB

  prep_weights<<<dim3(128, 6), 256, 0, stream>>>(W_q, W_k, W_v, W_o, w1, w2,
                                                 wqkvT, woT, w1b, w2b);
  ln_cast<true><<<8192, 128, 0, stream>>>(Q, ln1_g, ln1_b, Qn, K, V, Kb, Vb);
  gemm_qkv<<<dim3(64, 12), 256, 0, stream>>>(Qn, Kb, Vb, wqkvT, qb, kb, vtb);
  attn_kernel<<<dim3(16, 32), 512, 0, stream>>>(qb, kb, vtb, ctx);
  gemm_bt<2, 64, 4><<<dim3(64, 8), 256, 0, stream>>>(ctx, woT, 8192, 512, 512, X, nullptr, Q);
  ln_cast<false><<<8192, 128, 0, stream>>>(X, ln2_g, ln2_b, Xn, nullptr, nullptr, nullptr, nullptr);
  gemm_bt<3, 128, 4><<<dim3(64, 16), 256, 0, stream>>>(Xn, w1b, 8192, 2048, 512, hb, b1, nullptr);
  gemm_bt<4, 64, 4><<<dim3(64, 8), 256, 0, stream>>>(hb, w2b, 8192, 512, 2048, (float*)d_out, b2, X);
}

// Round 15
// 317.630 us; speedup vs baseline: 1.0224x; 1.0224x over previous
//
#include <hip/hip_runtime.h>

typedef unsigned short u16;
typedef __attribute__((ext_vector_type(8))) short short8;
typedef __attribute__((ext_vector_type(4))) float f32x4;
typedef __attribute__((ext_vector_type(16))) float f32x16;
typedef __attribute__((ext_vector_type(4))) unsigned u32x4;

struct __align__(8) us4 { u16 x, y, z, w; };
struct __align__(8) ui2 { unsigned x, y; };

// log2(e) / (sqrt(64) + 1e-6)  -- folded into W_q at prep time
#define CEXP (1.44269504089f / (8.0f + 1e-6f))

// ---------- helpers ----------
__device__ __forceinline__ u16 f2bf(float f) {
  unsigned u = __builtin_bit_cast(unsigned, f);
  unsigned r = (u + 0x7FFFu + ((u >> 16) & 1u)) >> 16;  // RNE
  return (u16)r;
}

// truncation pack: {bf16(b)[hi16] , bf16(a)[lo16]} in ONE v_perm_b32
__device__ __forceinline__ unsigned pack_bf2_trunc(float a, float b) {
  return __builtin_amdgcn_perm(__builtin_bit_cast(unsigned, b),
                               __builtin_bit_cast(unsigned, a), 0x07060302u);
}

__device__ __forceinline__ void async_load16(const void* g, void* l) {
  __builtin_amdgcn_global_load_lds((const __attribute__((address_space(1))) void*)g,
                                   (__attribute__((address_space(3))) void*)l, 16, 0, 0);
}

// ---------- weight prep ----------
// wqkvT: [1536,512] bf16 (rows 0-511 = Wq^T*CEXP, 512-1023 = Wk^T, 1024-1535 = Wv^T)
__global__ void prep_weights(const float* __restrict__ Wq, const float* __restrict__ Wk,
                             const float* __restrict__ Wv, const float* __restrict__ Wo,
                             const float* __restrict__ w1, const float* __restrict__ w2,
                             u16* __restrict__ wqkvT, u16* __restrict__ woT,
                             u16* __restrict__ w1b, u16* __restrict__ w2b) {
  const int z = blockIdx.y;
  const int stride = gridDim.x * blockDim.x;
  const int i0 = blockIdx.x * blockDim.x + threadIdx.x;
  if (z < 4) {
    const float* src = z == 0 ? Wq : z == 1 ? Wk : z == 2 ? Wv : Wo;
    u16* dst = z < 3 ? wqkvT + z * 512 * 512 : woT;
    const float scale = (z == 0) ? CEXP : 1.0f;
    for (int i = i0; i < 512 * 512; i += stride) {
      int n = i >> 9, k = i & 511;
      dst[i] = f2bf(src[k * 512 + n] * scale);   // out[n*512+k] = in[k,n]
    }
  } else {
    const float* src = z == 4 ? w1 : w2;
    u16* dst = z == 4 ? w1b : w2b;
    for (int i = i0; i < 2048 * 512; i += stride) dst[i] = f2bf(src[i]);
  }
}

// ---------- LayerNorm row kernel (+ optional bf16 cast of K,V rows) ----------
template <bool KV>
__launch_bounds__(128)
__global__ void ln_cast(const float* __restrict__ X, const float* __restrict__ gw,
                        const float* __restrict__ bw, u16* __restrict__ Y,
                        const float* __restrict__ Kin, const float* __restrict__ Vin,
                        u16* __restrict__ Kb, u16* __restrict__ Vb) {
  const int row = blockIdx.x, t = threadIdx.x;
  const size_t base = (size_t)row * 512;
  float4 x = ((const float4*)(X + base))[t];
  float s = x.x + x.y + x.z + x.w;
  float ss = x.x * x.x + x.y * x.y + x.z * x.z + x.w * x.w;
#pragma unroll
  for (int off = 32; off > 0; off >>= 1) {
    s += __shfl_xor(s, off);
    ss += __shfl_xor(ss, off);
  }
  __shared__ float red[4];
  if ((t & 63) == 0) { red[(t >> 6) * 2] = s; red[(t >> 6) * 2 + 1] = ss; }
  __syncthreads();
  const float tot = red[0] + red[2], tss = red[1] + red[3];
  const float mu = tot * (1.0f / 512.0f);
  const float var = tss * (1.0f / 512.0f) - mu * mu;
  const float rs = rsqrtf(var + 1e-5f);
  float4 g4 = ((const float4*)gw)[t];
  float4 b4 = ((const float4*)bw)[t];
  us4 o;
  o.x = f2bf((x.x - mu) * rs * g4.x + b4.x);
  o.y = f2bf((x.y - mu) * rs * g4.y + b4.y);
  o.z = f2bf((x.z - mu) * rs * g4.z + b4.z);
  o.w = f2bf((x.w - mu) * rs * g4.w + b4.w);
  ((us4*)(Y + base))[t] = o;
  if constexpr (KV) {
    float4 k4 = ((const float4*)(Kin + base))[t];
    float4 v4 = ((const float4*)(Vin + base))[t];
    us4 ko, vo;
    ko.x = f2bf(k4.x); ko.y = f2bf(k4.y); ko.z = f2bf(k4.z); ko.w = f2bf(k4.w);
    vo.x = f2bf(v4.x); vo.y = f2bf(v4.y); vo.z = f2bf(v4.z); vo.w = f2bf(v4.w);
    ((us4*)(Kb + base))[t] = ko;
    ((us4*)(Vb + base))[t] = vo;
  }
}

// ---------- merged QKV projection GEMM (XOR-swizzled LDS chunks) ----------
// 2-PHASE: prologue-stage buf0; per BK=32 step stage buf(t+1) BEFORE computing
// buf(t); one __syncthreads per step (prefetch latency hides under the 16 MFMAs;
// the old structure drained the just-issued loads before every compute).
__launch_bounds__(256, 4)
__global__ void gemm_qkv(const u16* __restrict__ Aq, const u16* __restrict__ Ak,
                         const u16* __restrict__ Av, const u16* __restrict__ Bt,
                         u16* __restrict__ qb, u16* __restrict__ kb, u16* __restrict__ vtb) {
  __shared__ __align__(16) u16 sA[2][128 * 32];
  __shared__ __align__(16) u16 sB[2][128 * 32];
  const int tid = threadIdx.x;
  const int wave = tid >> 6, lane = tid & 63;
  const int l15 = lane & 15, quad = lane >> 4;
  const int qsw = (quad ^ ((l15 >> 1) & 3)) * 8;
  const int m0 = blockIdx.x * 128, n0 = blockIdx.y * 128;
  const int sel = n0 >> 9;  // 0=q, 1=k, 2=v
  const u16* A = sel == 0 ? Aq : sel == 1 ? Ak : Av;
  const int wm = (wave >> 1) * 64, wn = (wave & 1) * 64;
  const int u0 = wave * 64 + lane, u1 = u0 + 256;
  const int sw0 = ((u0 & 3) ^ ((u0 >> 3) & 3)) * 8;  // same value for u1
  const int K = 512;

  const u16* a0 = A + (size_t)(m0 + (u0 >> 2)) * K + sw0;
  const u16* a1 = A + (size_t)(m0 + (u1 >> 2)) * K + sw0;
  const u16* b0 = Bt + (size_t)(n0 + (u0 >> 2)) * K + sw0;
  const u16* b1p = Bt + (size_t)(n0 + (u1 >> 2)) * K + sw0;

#define QSTAGE(bi, kk)                                       \
  {                                                          \
    async_load16(a0 + (kk), &sA[bi][wave * 512]);            \
    async_load16(a1 + (kk), &sA[bi][2048 + wave * 512]);     \
    async_load16(b0 + (kk), &sB[bi][wave * 512]);            \
    async_load16(b1p + (kk), &sB[bi][2048 + wave * 512]);    \
  }
#define QBODY(bi, tt)                                                            \
  {                                                                              \
    if ((tt) < 15) QSTAGE((bi) ^ 1, ((tt) + 1) * 32);                            \
    short8 af[4], bfr[4];                                                        \
    _Pragma("unroll") for (int i = 0; i < 4; i++)                                \
        af[i] = *(const short8*)&sA[bi][(wm + i * 16 + l15) * 32 + qsw];         \
    _Pragma("unroll") for (int j = 0; j < 4; j++)                                \
        bfr[j] = *(const short8*)&sB[bi][(wn + j * 16 + l15) * 32 + qsw];        \
    _Pragma("unroll") for (int i = 0; i < 4; i++)                                \
        _Pragma("unroll") for (int j = 0; j < 4; j++)                            \
            acc[i][j] =                                                          \
                __builtin_amdgcn_mfma_f32_16x16x32_bf16(af[i], bfr[j], acc[i][j], 0, 0, 0); \
    __syncthreads();                                                             \
  }

  f32x4 acc[4][4] = {};
  QSTAGE(0, 0);
  __syncthreads();
  for (int t = 0; t < 16; t += 2) {
    QBODY(0, t);
    QBODY(1, t + 1);
  }
#undef QBODY
#undef QSTAGE

#pragma unroll
  for (int i = 0; i < 4; i++) {
#pragma unroll
    for (int j = 0; j < 4; j++) {
      const int ocol = ((n0 + wn) & 511) + j * 16 + l15;
      const int row0 = m0 + wm + i * 16 + quad * 4;
      if (sel < 2) {
        u16* C = sel == 0 ? qb : kb;
#pragma unroll
        for (int r = 0; r < 4; r++) C[(size_t)(row0 + r) * 512 + ocol] = f2bf(acc[i][j][r]);
      } else {
        const int b = row0 >> 12, s0 = row0 & 4095;
        const int hh = ocol >> 6, cc = ocol & 63;
        us4 pk;
        pk.x = f2bf(acc[i][j][0]); pk.y = f2bf(acc[i][j][1]);
        pk.z = f2bf(acc[i][j][2]); pk.w = f2bf(acc[i][j][3]);
        *(us4*)&vtb[((size_t)((b * 8 + hh) * 64 + cc) << 12) + s0] = pk;
      }
    }
  }
}

// ---------- GEMM: C[M,N] = A[M,K] @ Bt[N,K]^T (XOR-swizzled LDS chunks) ----------
// 2-PHASE prefetch (see gemm_qkv). nt = K/32 (always even here). LB=4 -> 4 blocks/CU.
// EP: 2 = fp32 store + res add | 3 = +bias, exact GELU, bf16 | 4 = +bias +res, fp32
template <int EP, int TN, int LB>
__launch_bounds__(256, LB)
__global__ void gemm_bt(const u16* __restrict__ A, const u16* __restrict__ Bt,
                        int M, int N, int K, void* __restrict__ Cp,
                        const float* __restrict__ bias, const float* __restrict__ res) {
  constexpr int MI = (TN == 128) ? 4 : 2;
  __shared__ __align__(16) u16 sA[2][128 * 32];
  __shared__ __align__(16) u16 sB[2][TN * 32];
  const int tid = threadIdx.x;
  const int wave = tid >> 6, lane = tid & 63;
  const int l15 = lane & 15, quad = lane >> 4;
  const int qsw = (quad ^ ((l15 >> 1) & 3)) * 8;
  const int m0 = blockIdx.x * 128, n0 = blockIdx.y * TN;
  const int wm = (TN == 128) ? (wave >> 1) * 64 : wave * 32;
  const int wn = (TN == 128) ? (wave & 1) * 64 : 0;
  const int u0 = wave * 64 + lane, u1 = u0 + 256;
  const int sw0 = ((u0 & 3) ^ ((u0 >> 3) & 3)) * 8;

  const u16* a0 = A + (size_t)(m0 + (u0 >> 2)) * K + sw0;
  const u16* a1 = A + (size_t)(m0 + (u1 >> 2)) * K + sw0;
  const u16* b0 = Bt + (size_t)(n0 + (u0 >> 2)) * K + sw0;
  const u16* b1p = Bt + (size_t)(n0 + (u1 >> 2)) * K + sw0;
  const int nt = K >> 5;

#define GSTAGE(bi, kk)                                        \
  {                                                           \
    async_load16(a0 + (kk), &sA[bi][wave * 512]);             \
    async_load16(a1 + (kk), &sA[bi][2048 + wave * 512]);      \
    async_load16(b0 + (kk), &sB[bi][wave * 512]);             \
    if constexpr (TN == 128)                                  \
      async_load16(b1p + (kk), &sB[bi][2048 + wave * 512]);   \
  }
#define GBODY(bi, tt)                                                            \
  {                                                                              \
    if ((tt) < nt - 1) GSTAGE((bi) ^ 1, ((tt) + 1) * 32);                        \
    short8 af[MI], bfr[4];                                                       \
    _Pragma("unroll") for (int i = 0; i < MI; i++)                               \
        af[i] = *(const short8*)&sA[bi][(wm + i * 16 + l15) * 32 + qsw];         \
    _Pragma("unroll") for (int j = 0; j < 4; j++)                                \
        bfr[j] = *(const short8*)&sB[bi][(wn + j * 16 + l15) * 32 + qsw];        \
    _Pragma("unroll") for (int i = 0; i < MI; i++)                               \
        _Pragma("unroll") for (int j = 0; j < 4; j++)                            \
            acc[i][j] =                                                          \
                __builtin_amdgcn_mfma_f32_16x16x32_bf16(af[i], bfr[j], acc[i][j], 0, 0, 0); \
    __syncthreads();                                                             \
  }

  f32x4 acc[MI][4] = {};
  GSTAGE(0, 0);
  __syncthreads();
  for (int t = 0; t < nt; t += 2) {
    GBODY(0, t);
    GBODY(1, t + 1);
  }
#undef GBODY
#undef GSTAGE

#pragma unroll
  for (int i = 0; i < MI; i++) {
#pragma unroll
    for (int j = 0; j < 4; j++) {
      const int col = n0 + wn + j * 16 + l15;
      const int row0 = m0 + wm + i * 16 + quad * 4;
      if (EP == 2) {
        float* C = (float*)Cp;
#pragma unroll
        for (int r = 0; r < 4; r++) {
          size_t idx = (size_t)(row0 + r) * N + col;
          C[idx] = acc[i][j][r] + res[idx];
        }
      } else if (EP == 3) {
        u16* C = (u16*)Cp;
        const float bv = bias[col];
#pragma unroll
        for (int r = 0; r < 4; r++) {
          float xx = acc[i][j][r] + bv;
          float gl = 0.5f * xx * (1.0f + erff(xx * 0.70710678118f));
          C[(size_t)(row0 + r) * N + col] = f2bf(gl);
        }
      } else {
        float* C = (float*)Cp;
        const float bv = bias[col];
#pragma unroll
        for (int r = 0; r < 4; r++) {
          size_t idx = (size_t)(row0 + r) * N + col;
          C[idx] = acc[i][j][r] + bv + res[idx];
        }
      }
    }
  }
}

// ---------- flash attention (ROUND-9 version verbatim — measured best 80.0 us) ----------
// 8 waves x 512 threads = 4 q-groups (32 q each) x 2 key-halves; q-tile 128.
// grid (16 bh, 32 qt) = 512 blocks = exactly 2/CU; 4 waves/SIMD.
// Triple-buffered 64-key K/V tiles via global_load_lds, counted vmcnt, loop unrolled
// x3 so buffer indices are compile-time; XCD-local grid (wg id = bh + 16*qt -> XCD =
// bh%8; FETCH 12.3 MB); in-register P via pack+permlane32_swap; 2-way key merge.
__launch_bounds__(512, 2)
__global__ void attn_kernel(const u16* __restrict__ qb, const u16* __restrict__ kb,
                            const u16* __restrict__ vtb, u16* __restrict__ ctx) {
  // u16 layout: K bufs at bi*4096 (bi=0..2), V bufs at 12288 + bi*4096. 48 KB.
  // merge reuse as float*: ov region [0,8192), l at [8192,8448).
  __shared__ __align__(16) u16 smem[24576];
  const int tid = threadIdx.x;
  const int wave = tid >> 6, lane = tid & 63;
  const int l31 = lane & 31, hi = lane >> 5;
  const int qg = wave >> 1, kh = wave & 1;
  const int bh = blockIdx.x, b = bh >> 3, h = bh & 7;
  const int q0 = blockIdx.y * 128;
  const size_t rb = (size_t)b * 4096;
  const int qrow = q0 + qg * 32 + l31;

  // Q B-fragment: qf[ks] elem e -> Q[qrow][h*64 + ks*16 + hi*8 + e]
  short8 qf[4];
#pragma unroll
  for (int ks = 0; ks < 4; ks++)
    qf[ks] = *(const short8*)&qb[(rb + qrow) * 512 + h * 64 + ks * 16 + hi * 8];

  // loop-invariant per-lane LDS read offsets (u16 units within one buffer)
  const int krow = kh * 32 + l31;
  int koff[4];
#pragma unroll
  for (int ks = 0; ks < 4; ks++)
    koff[ks] = krow * 64 + (((ks * 2 + hi) ^ (krow & 7))) * 8;
  int voff[2][2];
#pragma unroll
  for (int vb = 0; vb < 2; vb++) {
    const int vrow = vb * 32 + l31;
    voff[vb][0] = vrow * 64 + (((kh * 4 + hi) ^ (vrow & 7))) * 8;
    voff[vb][1] = vrow * 64 + (((kh * 4 + 2 + hi) ^ (vrow & 7))) * 8;
  }

  // staging: 64-key tile = K 512 + V 512 16B-units; 512 threads x (1 K + 1 V).
  const int srow = tid >> 3, ssl = (tid & 7) ^ (srow & 7);
  const u16* kp = kb + (rb + srow) * 512 + h * 64 + ssl * 8;
  const u16* vp = vtb + (size_t)(bh * 64 + srow) * 4096 + ssl * 8;
  const int sdst = tid * 8;  // u16 units

  f32x16 ov[2] = {};
  float l_part = 0.f;

  // prologue: stage buffers 0 and 1
  async_load16(kp, &smem[sdst]);
  async_load16(vp, &smem[12288 + sdst]);
  kp += 64 * 512; vp += 64;
  async_load16(kp, &smem[4096 + sdst]);
  async_load16(vp, &smem[12288 + 4096 + sdst]);
  kp += 64 * 512; vp += 64;
  asm volatile("s_waitcnt vmcnt(2)" ::: "memory");
  __syncthreads();

  // BODY(CUR, TT): compute tile TT from buffer CUR (compile-time), staging buffer
  // (CUR+2)%3 for tile TT+2 when TT<62; counted-vmcnt barrier unless last tile.
#define BODY(CUR, TT)                                                              \
  {                                                                                \
    if ((TT) < 62) {                                                               \
      async_load16(kp, &smem[(((CUR) + 2) % 3) * 4096 + sdst]);                    \
      async_load16(vp, &smem[12288 + (((CUR) + 2) % 3) * 4096 + sdst]);            \
      kp += 64 * 512; vp += 64;                                                    \
    }                                                                              \
    f32x16 st = {};                                                                \
    __builtin_amdgcn_s_setprio(1);                                                 \
    _Pragma("unroll") for (int ks = 0; ks < 4; ks++) {                             \
      short8 kf = *(const short8*)&smem[(CUR) * 4096 + koff[ks]];                  \
      st = __builtin_amdgcn_mfma_f32_32x32x16_bf16(kf, qf[ks], st, 0, 0, 0);       \
    }                                                                              \
    __builtin_amdgcn_s_setprio(0);                                                 \
    float p[16];                                                                   \
    _Pragma("unroll") for (int i = 0; i < 16; i++)                                 \
        p[i] = __builtin_amdgcn_exp2f(st[i]);                                      \
    _Pragma("unroll") for (int i = 0; i < 16; i += 4)                              \
        l_part += (p[i] + p[i + 1]) + (p[i + 2] + p[i + 3]);                       \
    unsigned x0 = pack_bf2_trunc(p[0], p[1]), x1 = pack_bf2_trunc(p[2], p[3]);     \
    unsigned x2 = pack_bf2_trunc(p[4], p[5]), x3 = pack_bf2_trunc(p[6], p[7]);     \
    unsigned x4 = pack_bf2_trunc(p[8], p[9]), x5 = pack_bf2_trunc(p[10], p[11]);   \
    unsigned x6 = pack_bf2_trunc(p[12], p[13]), x7 = pack_bf2_trunc(p[14], p[15]); \
    auto r0 = __builtin_amdgcn_permlane32_swap(x0, x2, false, false);              \
    auto r1 = __builtin_amdgcn_permlane32_swap(x1, x3, false, false);              \
    auto r2 = __builtin_amdgcn_permlane32_swap(x4, x6, false, false);              \
    auto r3 = __builtin_amdgcn_permlane32_swap(x5, x7, false, false);              \
    u32x4 w0 = {r0[0], r1[0], r0[1], r1[1]};                                       \
    u32x4 w1 = {r2[0], r3[0], r2[1], r3[1]};                                       \
    short8 pf0 = __builtin_bit_cast(short8, w0);                                   \
    short8 pf1 = __builtin_bit_cast(short8, w1);                                   \
    __builtin_amdgcn_s_setprio(1);                                                 \
    _Pragma("unroll") for (int vb = 0; vb < 2; vb++) {                             \
      short8 vf0 = *(const short8*)&smem[12288 + (CUR) * 4096 + voff[vb][0]];      \
      short8 vf1 = *(const short8*)&smem[12288 + (CUR) * 4096 + voff[vb][1]];      \
      ov[vb] = __builtin_amdgcn_mfma_f32_32x32x16_bf16(vf0, pf0, ov[vb], 0, 0, 0); \
      ov[vb] = __builtin_amdgcn_mfma_f32_32x32x16_bf16(vf1, pf1, ov[vb], 0, 0, 0); \
    }                                                                              \
    __builtin_amdgcn_s_setprio(0);                                                 \
    if ((TT) < 63) {                                                               \
      if ((TT) < 62)                                                               \
        asm volatile("s_waitcnt vmcnt(2)" ::: "memory");                           \
      else                                                                         \
        asm volatile("s_waitcnt vmcnt(0)" ::: "memory");                           \
      __syncthreads();                                                             \
    }                                                                              \
  }

  // 64 tiles: 21 unrolled groups of 3 (t = 0..62) + tail t = 63 (buffer 0).
  for (int g = 0; g < 21; g++) {
    const int t0 = g * 3;
    BODY(0, t0);
    BODY(1, t0 + 1);
    BODY(2, t0 + 2);
  }
  BODY(0, 63);
#undef BODY

  // ---- 2-way key-split merge through LDS (reuse staging space) ----
  float l2 = l_part + __shfl_xor(l_part, 32);
  __syncthreads();  // all compute reads of smem done before reuse
  float* mrg = (float*)smem;           // (qg*32 + vb*16 + e)*64 + lane : 32 KB
  float* mrgl = (float*)smem + 8192;   // qg*64 + lane : 1 KB
  if (kh == 1) {
#pragma unroll
    for (int vb = 0; vb < 2; vb++)
#pragma unroll
      for (int e = 0; e < 16; e++)
        mrg[(qg * 32 + vb * 16 + e) * 64 + lane] = ov[vb][e];
    mrgl[qg * 64 + lane] = l2;
  }
  __syncthreads();
  if (kh == 0) {
    const float inv = 1.0f / (l2 + mrgl[qg * 64 + lane]);
#pragma unroll
    for (int vb = 0; vb < 2; vb++) {
#pragma unroll
      for (int rg = 0; rg < 4; rg++) {
        us4 o;
        o.x = f2bf((ov[vb][rg * 4 + 0] + mrg[(qg * 32 + vb * 16 + rg * 4 + 0) * 64 + lane]) * inv);
        o.y = f2bf((ov[vb][rg * 4 + 1] + mrg[(qg * 32 + vb * 16 + rg * 4 + 1) * 64 + lane]) * inv);
        o.z = f2bf((ov[vb][rg * 4 + 2] + mrg[(qg * 32 + vb * 16 + rg * 4 + 2) * 64 + lane]) * inv);
        o.w = f2bf((ov[vb][rg * 4 + 3] + mrg[(qg * 32 + vb * 16 + rg * 4 + 3) * 64 + lane]) * inv);
        *(us4*)&ctx[(rb + qrow) * 512 + h * 64 + vb * 32 + rg * 8 + hi * 4] = o;
      }
    }
  }
}

// ---------- launch ----------
extern "C" void kernel_launch(void* const* d_in, const int* in_sizes, int n_in,
                              void* d_out, int out_size, void* d_ws, size_t ws_size,
                              hipStream_t stream) {
  (void)in_sizes; (void)n_in; (void)out_size; (void)ws_size;
  const float* Q = (const float*)d_in[0];
  const float* K = (const float*)d_in[1];
  const float* V = (const float*)d_in[2];
  const float* W_q = (const float*)d_in[3];
  const float* W_k = (const float*)d_in[4];
  const float* W_v = (const float*)d_in[5];
  const float* W_o = (const float*)d_in[6];
  const float* ln1_g = (const float*)d_in[7];
  const float* ln1_b = (const float*)d_in[8];
  const float* ln2_g = (const float*)d_in[9];
  const float* ln2_b = (const float*)d_in[10];
  const float* w1 = (const float*)d_in[11];
  const float* b1 = (const float*)d_in[12];
  const float* w2 = (const float*)d_in[13];
  const float* b2 = (const float*)d_in[14];

  char* w = (char*)d_ws;
  const size_t MB = 1u << 20;
  u16* wqkvT = (u16*)(w);                       // 1.5 MB [1536,512]
  u16* woT = (u16*)(w + 3 * MB / 2);            // 0.5 MB
  u16* w1b = (u16*)(w + 2 * MB);                // 2 MB
  u16* w2b = (u16*)(w + 4 * MB);                // 2 MB
  u16* Qn  = (u16*)(w + 6 * MB);                // 8 MB
  u16* Kb  = (u16*)(w + 14 * MB);               // 8 MB
  u16* Vb  = (u16*)(w + 22 * MB);               // 8 MB
  u16* qb  = (u16*)(w + 30 * MB);               // 8 MB
  u16* kb  = (u16*)(w + 38 * MB);               // 8 MB (row-major K)
  u16* vtb = (u16*)(w + 46 * MB);               // 8 MB ([bh*64+dv][4096] V)
  u16* ctx = (u16*)(w + 54 * MB);               // 8 MB
  float* X = (float*)(w + 62 * MB);             // 16 MB
  u16* Xn  = (u16*)(w + 6 * MB);                // reuse Qn
  u16* hb  = (u16*)(w + 14 * MB);               // reuse Kb/Vb/qb, 32 MB

  prep_weights<<<dim3(128, 6), 256, 0, stream>>>(W_q, W_k, W_v, W_o, w1, w2,
                                                 wqkvT, woT, w1b, w2b);
  ln_cast<true><<<8192, 128, 0, stream>>>(Q, ln1_g, ln1_b, Qn, K, V, Kb, Vb);
  gemm_qkv<<<dim3(64, 12), 256, 0, stream>>>(Qn, Kb, Vb, wqkvT, qb, kb, vtb);
  attn_kernel<<<dim3(16, 32), 512, 0, stream>>>(qb, kb, vtb, ctx);
  gemm_bt<2, 64, 4><<<dim3(64, 8), 256, 0, stream>>>(ctx, woT, 8192, 512, 512, X, nullptr, Q);
  ln_cast<false><<<8192, 128, 0, stream>>>(X, ln2_g, ln2_b, Xn, nullptr, nullptr, nullptr, nullptr);
  gemm_bt<3, 128, 4><<<dim3(64, 16), 256, 0, stream>>>(Xn, w1b, 8192, 2048, 512, hb, b1, nullptr);
  gemm_bt<4, 64, 4><<<dim3(64, 8), 256, 0, stream>>>(hb, w2b, 8192, 512, 2048, (float*)d_out, b2, X);
}

// Round 16
// 300.199 us; speedup vs baseline: 1.0817x; 1.0581x over previous
//
#include <hip/hip_runtime.h>

typedef unsigned short u16;
typedef __attribute__((ext_vector_type(8))) short short8;
typedef __attribute__((ext_vector_type(4))) float f32x4;
typedef __attribute__((ext_vector_type(16))) float f32x16;
typedef __attribute__((ext_vector_type(4))) unsigned u32x4;

struct __align__(8) us4 { u16 x, y, z, w; };
struct __align__(8) ui2 { unsigned x, y; };

// log2(e) / (sqrt(64) + 1e-6)  -- folded into W_q at prep time
#define CEXP (1.44269504089f / (8.0f + 1e-6f))

// ---------- helpers ----------
__device__ __forceinline__ u16 f2bf(float f) {
  unsigned u = __builtin_bit_cast(unsigned, f);
  unsigned r = (u + 0x7FFFu + ((u >> 16) & 1u)) >> 16;  // RNE
  return (u16)r;
}

// truncation pack: {bf16(b)[hi16] , bf16(a)[lo16]} in ONE v_perm_b32
__device__ __forceinline__ unsigned pack_bf2_trunc(float a, float b) {
  return __builtin_amdgcn_perm(__builtin_bit_cast(unsigned, b),
                               __builtin_bit_cast(unsigned, a), 0x07060302u);
}

__device__ __forceinline__ void async_load16(const void* g, void* l) {
  __builtin_amdgcn_global_load_lds((const __attribute__((address_space(1))) void*)g,
                                   (__attribute__((address_space(3))) void*)l, 16, 0, 0);
}

// ---------- weight prep ----------
// wqkvT: [1536,512] bf16 (rows 0-511 = Wq^T*CEXP, 512-1023 = Wk^T, 1024-1535 = Wv^T)
__global__ void prep_weights(const float* __restrict__ Wq, const float* __restrict__ Wk,
                             const float* __restrict__ Wv, const float* __restrict__ Wo,
                             const float* __restrict__ w1, const float* __restrict__ w2,
                             u16* __restrict__ wqkvT, u16* __restrict__ woT,
                             u16* __restrict__ w1b, u16* __restrict__ w2b) {
  const int z = blockIdx.y;
  const int stride = gridDim.x * blockDim.x;
  const int i0 = blockIdx.x * blockDim.x + threadIdx.x;
  if (z < 4) {
    const float* src = z == 0 ? Wq : z == 1 ? Wk : z == 2 ? Wv : Wo;
    u16* dst = z < 3 ? wqkvT + z * 512 * 512 : woT;
    const float scale = (z == 0) ? CEXP : 1.0f;
    for (int i = i0; i < 512 * 512; i += stride) {
      int n = i >> 9, k = i & 511;
      dst[i] = f2bf(src[k * 512 + n] * scale);   // out[n*512+k] = in[k,n]
    }
  } else {
    const float* src = z == 4 ? w1 : w2;
    u16* dst = z == 4 ? w1b : w2b;
    for (int i = i0; i < 2048 * 512; i += stride) dst[i] = f2bf(src[i]);
  }
}

// ---------- LayerNorm row kernel (+ optional bf16 cast of K,V rows) ----------
template <bool KV>
__launch_bounds__(128)
__global__ void ln_cast(const float* __restrict__ X, const float* __restrict__ gw,
                        const float* __restrict__ bw, u16* __restrict__ Y,
                        const float* __restrict__ Kin, const float* __restrict__ Vin,
                        u16* __restrict__ Kb, u16* __restrict__ Vb) {
  const int row = blockIdx.x, t = threadIdx.x;
  const size_t base = (size_t)row * 512;
  float4 x = ((const float4*)(X + base))[t];
  float s = x.x + x.y + x.z + x.w;
  float ss = x.x * x.x + x.y * x.y + x.z * x.z + x.w * x.w;
#pragma unroll
  for (int off = 32; off > 0; off >>= 1) {
    s += __shfl_xor(s, off);
    ss += __shfl_xor(ss, off);
  }
  __shared__ float red[4];
  if ((t & 63) == 0) { red[(t >> 6) * 2] = s; red[(t >> 6) * 2 + 1] = ss; }
  __syncthreads();
  const float tot = red[0] + red[2], tss = red[1] + red[3];
  const float mu = tot * (1.0f / 512.0f);
  const float var = tss * (1.0f / 512.0f) - mu * mu;
  const float rs = rsqrtf(var + 1e-5f);
  float4 g4 = ((const float4*)gw)[t];
  float4 b4 = ((const float4*)bw)[t];
  us4 o;
  o.x = f2bf((x.x - mu) * rs * g4.x + b4.x);
  o.y = f2bf((x.y - mu) * rs * g4.y + b4.y);
  o.z = f2bf((x.z - mu) * rs * g4.z + b4.z);
  o.w = f2bf((x.w - mu) * rs * g4.w + b4.w);
  ((us4*)(Y + base))[t] = o;
  if constexpr (KV) {
    float4 k4 = ((const float4*)(Kin + base))[t];
    float4 v4 = ((const float4*)(Vin + base))[t];
    us4 ko, vo;
    ko.x = f2bf(k4.x); ko.y = f2bf(k4.y); ko.z = f2bf(k4.z); ko.w = f2bf(k4.w);
    vo.x = f2bf(v4.x); vo.y = f2bf(v4.y); vo.z = f2bf(v4.z); vo.w = f2bf(v4.w);
    ((us4*)(Kb + base))[t] = ko;
    ((us4*)(Vb + base))[t] = vo;
  }
}

// ---------- merged QKV projection GEMM (round-12 structure: dual 32-K sub-tiles,
// stage-all -> drain -> compute; one drain per 64-K) ----------
__launch_bounds__(256, 4)
__global__ void gemm_qkv(const u16* __restrict__ Aq, const u16* __restrict__ Ak,
                         const u16* __restrict__ Av, const u16* __restrict__ Bt,
                         u16* __restrict__ qb, u16* __restrict__ kb, u16* __restrict__ vtb) {
  __shared__ __align__(16) u16 sA[2][128 * 32];
  __shared__ __align__(16) u16 sB[2][128 * 32];
  const int tid = threadIdx.x;
  const int wave = tid >> 6, lane = tid & 63;
  const int l15 = lane & 15, quad = lane >> 4;
  const int qsw = (quad ^ ((l15 >> 1) & 3)) * 8;
  const int m0 = blockIdx.x * 128, n0 = blockIdx.y * 128;
  const int sel = n0 >> 9;  // 0=q, 1=k, 2=v
  const u16* A = sel == 0 ? Aq : sel == 1 ? Ak : Av;
  const int wm = (wave >> 1) * 64, wn = (wave & 1) * 64;
  const int u0 = wave * 64 + lane, u1 = u0 + 256;
  const int sw0 = ((u0 & 3) ^ ((u0 >> 3) & 3)) * 8;  // same value for u1
  const int K = 512;

  const u16* a0 = A + (size_t)(m0 + (u0 >> 2)) * K + sw0;
  const u16* a1 = A + (size_t)(m0 + (u1 >> 2)) * K + sw0;
  const u16* b0 = Bt + (size_t)(n0 + (u0 >> 2)) * K + sw0;
  const u16* b1p = Bt + (size_t)(n0 + (u1 >> 2)) * K + sw0;

  f32x4 acc[4][4] = {};
  for (int k0 = 0; k0 < K; k0 += 64) {
#pragma unroll
    for (int hf = 0; hf < 2; hf++) {
      const int kk = k0 + hf * 32;
      async_load16(a0 + kk, &sA[hf][wave * 512]);
      async_load16(a1 + kk, &sA[hf][2048 + wave * 512]);
      async_load16(b0 + kk, &sB[hf][wave * 512]);
      async_load16(b1p + kk, &sB[hf][2048 + wave * 512]);
    }
    __syncthreads();
#pragma unroll
    for (int hf = 0; hf < 2; hf++) {
      short8 af[4], bfr[4];
#pragma unroll
      for (int i = 0; i < 4; i++)
        af[i] = *(const short8*)&sA[hf][(wm + i * 16 + l15) * 32 + qsw];
#pragma unroll
      for (int j = 0; j < 4; j++)
        bfr[j] = *(const short8*)&sB[hf][(wn + j * 16 + l15) * 32 + qsw];
#pragma unroll
      for (int i = 0; i < 4; i++)
#pragma unroll
        for (int j = 0; j < 4; j++)
          acc[i][j] = __builtin_amdgcn_mfma_f32_16x16x32_bf16(af[i], bfr[j], acc[i][j], 0, 0, 0);
    }
    __syncthreads();
  }

#pragma unroll
  for (int i = 0; i < 4; i++) {
#pragma unroll
    for (int j = 0; j < 4; j++) {
      const int ocol = ((n0 + wn) & 511) + j * 16 + l15;
      const int row0 = m0 + wm + i * 16 + quad * 4;
      if (sel < 2) {
        u16* C = sel == 0 ? qb : kb;
#pragma unroll
        for (int r = 0; r < 4; r++) C[(size_t)(row0 + r) * 512 + ocol] = f2bf(acc[i][j][r]);
      } else {
        const int b = row0 >> 12, s0 = row0 & 4095;
        const int hh = ocol >> 6, cc = ocol & 63;
        us4 pk;
        pk.x = f2bf(acc[i][j][0]); pk.y = f2bf(acc[i][j][1]);
        pk.z = f2bf(acc[i][j][2]); pk.w = f2bf(acc[i][j][3]);
        *(us4*)&vtb[((size_t)((b * 8 + hh) * 64 + cc) << 12) + s0] = pk;
      }
    }
  }
}

// ---------- GEMM: C[M,N] = A[M,K] @ Bt[N,K]^T (XOR-swizzled LDS chunks) ----------
// SUB independent 32-K sub-tiles per barrier pair (stage-all -> drain -> compute):
// one drain per SUB*32 K. Round-11 measured +11us going 1->2; TN=64 kernels (512-
// block grids, <=2 resident blocks/CU) go to SUB=4 (48 KB LDS, no occupancy cost).
// EP: 2 = fp32 store + res add | 3 = +bias, exact GELU, bf16 | 4 = +bias +res, fp32
template <int EP, int TN, int LB, int SUB>
__launch_bounds__(256, LB)
__global__ void gemm_bt(const u16* __restrict__ A, const u16* __restrict__ Bt,
                        int M, int N, int K, void* __restrict__ Cp,
                        const float* __restrict__ bias, const float* __restrict__ res) {
  constexpr int MI = (TN == 128) ? 4 : 2;
  __shared__ __align__(16) u16 sA[SUB][128 * 32];
  __shared__ __align__(16) u16 sB[SUB][TN * 32];
  const int tid = threadIdx.x;
  const int wave = tid >> 6, lane = tid & 63;
  const int l15 = lane & 15, quad = lane >> 4;
  const int qsw = (quad ^ ((l15 >> 1) & 3)) * 8;
  const int m0 = blockIdx.x * 128, n0 = blockIdx.y * TN;
  const int wm = (TN == 128) ? (wave >> 1) * 64 : wave * 32;
  const int wn = (TN == 128) ? (wave & 1) * 64 : 0;
  const int u0 = wave * 64 + lane, u1 = u0 + 256;
  const int sw0 = ((u0 & 3) ^ ((u0 >> 3) & 3)) * 8;

  const u16* a0 = A + (size_t)(m0 + (u0 >> 2)) * K + sw0;
  const u16* a1 = A + (size_t)(m0 + (u1 >> 2)) * K + sw0;
  const u16* b0 = Bt + (size_t)(n0 + (u0 >> 2)) * K + sw0;

  f32x4 acc[MI][4] = {};
  for (int k0 = 0; k0 < K; k0 += SUB * 32) {
#pragma unroll
    for (int hf = 0; hf < SUB; hf++) {
      const int kk = k0 + hf * 32;
      async_load16(a0 + kk, &sA[hf][wave * 512]);
      async_load16(a1 + kk, &sA[hf][2048 + wave * 512]);
      async_load16(b0 + kk, &sB[hf][wave * 512]);
      if constexpr (TN == 128) {
        const u16* b1p = Bt + (size_t)(n0 + (u1 >> 2)) * K + sw0;
        async_load16(b1p + kk, &sB[hf][2048 + wave * 512]);
      }
    }
    __syncthreads();
#pragma unroll
    for (int hf = 0; hf < SUB; hf++) {
      short8 af[MI], bfr[4];
#pragma unroll
      for (int i = 0; i < MI; i++)
        af[i] = *(const short8*)&sA[hf][(wm + i * 16 + l15) * 32 + qsw];
#pragma unroll
      for (int j = 0; j < 4; j++)
        bfr[j] = *(const short8*)&sB[hf][(wn + j * 16 + l15) * 32 + qsw];
#pragma unroll
      for (int i = 0; i < MI; i++)
#pragma unroll
        for (int j = 0; j < 4; j++)
          acc[i][j] = __builtin_amdgcn_mfma_f32_16x16x32_bf16(af[i], bfr[j], acc[i][j], 0, 0, 0);
    }
    __syncthreads();
  }

#pragma unroll
  for (int i = 0; i < MI; i++) {
#pragma unroll
    for (int j = 0; j < 4; j++) {
      const int col = n0 + wn + j * 16 + l15;
      const int row0 = m0 + wm + i * 16 + quad * 4;
      if (EP == 2) {
        float* C = (float*)Cp;
#pragma unroll
        for (int r = 0; r < 4; r++) {
          size_t idx = (size_t)(row0 + r) * N + col;
          C[idx] = acc[i][j][r] + res[idx];
        }
      } else if (EP == 3) {
        u16* C = (u16*)Cp;
        const float bv = bias[col];
#pragma unroll
        for (int r = 0; r < 4; r++) {
          float xx = acc[i][j][r] + bv;
          float gl = 0.5f * xx * (1.0f + erff(xx * 0.70710678118f));
          C[(size_t)(row0 + r) * N + col] = f2bf(gl);
        }
      } else {
        float* C = (float*)Cp;
        const float bv = bias[col];
#pragma unroll
        for (int r = 0; r < 4; r++) {
          size_t idx = (size_t)(row0 + r) * N + col;
          C[idx] = acc[i][j][r] + bv + res[idx];
        }
      }
    }
  }
}

// ---------- flash attention (round-9 version — measured best 79.3-80.4 us) ----------
// 8 waves x 512 threads = 4 q-groups (32 q each) x 2 key-halves; q-tile 128.
// grid (16 bh, 32 qt) = 512 blocks = exactly 2/CU; 4 waves/SIMD.
// Triple-buffered 64-key K/V tiles via global_load_lds, counted vmcnt, loop unrolled
// x3 so buffer indices are compile-time; XCD-local grid (wg id = bh + 16*qt -> XCD =
// bh%8; FETCH 12.3 MB); in-register P via pack+permlane32_swap; 2-way key merge.
__launch_bounds__(512, 2)
__global__ void attn_kernel(const u16* __restrict__ qb, const u16* __restrict__ kb,
                            const u16* __restrict__ vtb, u16* __restrict__ ctx) {
  // u16 layout: K bufs at bi*4096 (bi=0..2), V bufs at 12288 + bi*4096. 48 KB.
  // merge reuse as float*: ov region [0,8192), l at [8192,8448).
  __shared__ __align__(16) u16 smem[24576];
  const int tid = threadIdx.x;
  const int wave = tid >> 6, lane = tid & 63;
  const int l31 = lane & 31, hi = lane >> 5;
  const int qg = wave >> 1, kh = wave & 1;
  const int bh = blockIdx.x, b = bh >> 3, h = bh & 7;
  const int q0 = blockIdx.y * 128;
  const size_t rb = (size_t)b * 4096;
  const int qrow = q0 + qg * 32 + l31;

  // Q B-fragment: qf[ks] elem e -> Q[qrow][h*64 + ks*16 + hi*8 + e]
  short8 qf[4];
#pragma unroll
  for (int ks = 0; ks < 4; ks++)
    qf[ks] = *(const short8*)&qb[(rb + qrow) * 512 + h * 64 + ks * 16 + hi * 8];

  // loop-invariant per-lane LDS read offsets (u16 units within one buffer)
  const int krow = kh * 32 + l31;
  int koff[4];
#pragma unroll
  for (int ks = 0; ks < 4; ks++)
    koff[ks] = krow * 64 + (((ks * 2 + hi) ^ (krow & 7))) * 8;
  int voff[2][2];
#pragma unroll
  for (int vb = 0; vb < 2; vb++) {
    const int vrow = vb * 32 + l31;
    voff[vb][0] = vrow * 64 + (((kh * 4 + hi) ^ (vrow & 7))) * 8;
    voff[vb][1] = vrow * 64 + (((kh * 4 + 2 + hi) ^ (vrow & 7))) * 8;
  }

  // staging: 64-key tile = K 512 + V 512 16B-units; 512 threads x (1 K + 1 V).
  const int srow = tid >> 3, ssl = (tid & 7) ^ (srow & 7);
  const u16* kp = kb + (rb + srow) * 512 + h * 64 + ssl * 8;
  const u16* vp = vtb + (size_t)(bh * 64 + srow) * 4096 + ssl * 8;
  const int sdst = tid * 8;  // u16 units

  f32x16 ov[2] = {};
  float l_part = 0.f;

  // prologue: stage buffers 0 and 1
  async_load16(kp, &smem[sdst]);
  async_load16(vp, &smem[12288 + sdst]);
  kp += 64 * 512; vp += 64;
  async_load16(kp, &smem[4096 + sdst]);
  async_load16(vp, &smem[12288 + 4096 + sdst]);
  kp += 64 * 512; vp += 64;
  asm volatile("s_waitcnt vmcnt(2)" ::: "memory");
  __syncthreads();

  // BODY(CUR, TT): compute tile TT from buffer CUR (compile-time), staging buffer
  // (CUR+2)%3 for tile TT+2 when TT<62; counted-vmcnt barrier unless last tile.
#define BODY(CUR, TT)                                                              \
  {                                                                                \
    if ((TT) < 62) {                                                               \
      async_load16(kp, &smem[(((CUR) + 2) % 3) * 4096 + sdst]);                    \
      async_load16(vp, &smem[12288 + (((CUR) + 2) % 3) * 4096 + sdst]);            \
      kp += 64 * 512; vp += 64;                                                    \
    }                                                                              \
    f32x16 st = {};                                                                \
    __builtin_amdgcn_s_setprio(1);                                                 \
    _Pragma("unroll") for (int ks = 0; ks < 4; ks++) {                             \
      short8 kf = *(const short8*)&smem[(CUR) * 4096 + koff[ks]];                  \
      st = __builtin_amdgcn_mfma_f32_32x32x16_bf16(kf, qf[ks], st, 0, 0, 0);       \
    }                                                                              \
    __builtin_amdgcn_s_setprio(0);                                                 \
    float p[16];                                                                   \
    _Pragma("unroll") for (int i = 0; i < 16; i++)                                 \
        p[i] = __builtin_amdgcn_exp2f(st[i]);                                      \
    _Pragma("unroll") for (int i = 0; i < 16; i += 4)                              \
        l_part += (p[i] + p[i + 1]) + (p[i + 2] + p[i + 3]);                       \
    unsigned x0 = pack_bf2_trunc(p[0], p[1]), x1 = pack_bf2_trunc(p[2], p[3]);     \
    unsigned x2 = pack_bf2_trunc(p[4], p[5]), x3 = pack_bf2_trunc(p[6], p[7]);     \
    unsigned x4 = pack_bf2_trunc(p[8], p[9]), x5 = pack_bf2_trunc(p[10], p[11]);   \
    unsigned x6 = pack_bf2_trunc(p[12], p[13]), x7 = pack_bf2_trunc(p[14], p[15]); \
    auto r0 = __builtin_amdgcn_permlane32_swap(x0, x2, false, false);              \
    auto r1 = __builtin_amdgcn_permlane32_swap(x1, x3, false, false);              \
    auto r2 = __builtin_amdgcn_permlane32_swap(x4, x6, false, false);              \
    auto r3 = __builtin_amdgcn_permlane32_swap(x5, x7, false, false);              \
    u32x4 w0 = {r0[0], r1[0], r0[1], r1[1]};                                       \
    u32x4 w1 = {r2[0], r3[0], r2[1], r3[1]};                                       \
    short8 pf0 = __builtin_bit_cast(short8, w0);                                   \
    short8 pf1 = __builtin_bit_cast(short8, w1);                                   \
    __builtin_amdgcn_s_setprio(1);                                                 \
    _Pragma("unroll") for (int vb = 0; vb < 2; vb++) {                             \
      short8 vf0 = *(const short8*)&smem[12288 + (CUR) * 4096 + voff[vb][0]];      \
      short8 vf1 = *(const short8*)&smem[12288 + (CUR) * 4096 + voff[vb][1]];      \
      ov[vb] = __builtin_amdgcn_mfma_f32_32x32x16_bf16(vf0, pf0, ov[vb], 0, 0, 0); \
      ov[vb] = __builtin_amdgcn_mfma_f32_32x32x16_bf16(vf1, pf1, ov[vb], 0, 0, 0); \
    }                                                                              \
    __builtin_amdgcn_s_setprio(0);                                                 \
    if ((TT) < 63) {                                                               \
      if ((TT) < 62)                                                               \
        asm volatile("s_waitcnt vmcnt(2)" ::: "memory");                           \
      else                                                                         \
        asm volatile("s_waitcnt vmcnt(0)" ::: "memory");                           \
      __syncthreads();                                                             \
    }                                                                              \
  }

  // 64 tiles: 21 unrolled groups of 3 (t = 0..62) + tail t = 63 (buffer 0).
  for (int g = 0; g < 21; g++) {
    const int t0 = g * 3;
    BODY(0, t0);
    BODY(1, t0 + 1);
    BODY(2, t0 + 2);
  }
  BODY(0, 63);
#undef BODY

  // ---- 2-way key-split merge through LDS (reuse staging space) ----
  float l2 = l_part + __shfl_xor(l_part, 32);
  __syncthreads();  // all compute reads of smem done before reuse
  float* mrg = (float*)smem;           // (qg*32 + vb*16 + e)*64 + lane : 32 KB
  float* mrgl = (float*)smem + 8192;   // qg*64 + lane : 1 KB
  if (kh == 1) {
#pragma unroll
    for (int vb = 0; vb < 2; vb++)
#pragma unroll
      for (int e = 0; e < 16; e++)
        mrg[(qg * 32 + vb * 16 + e) * 64 + lane] = ov[vb][e];
    mrgl[qg * 64 + lane] = l2;
  }
  __syncthreads();
  if (kh == 0) {
    const float inv = 1.0f / (l2 + mrgl[qg * 64 + lane]);
#pragma unroll
    for (int vb = 0; vb < 2; vb++) {
#pragma unroll
      for (int rg = 0; rg < 4; rg++) {
        us4 o;
        o.x = f2bf((ov[vb][rg * 4 + 0] + mrg[(qg * 32 + vb * 16 + rg * 4 + 0) * 64 + lane]) * inv);
        o.y = f2bf((ov[vb][rg * 4 + 1] + mrg[(qg * 32 + vb * 16 + rg * 4 + 1) * 64 + lane]) * inv);
        o.z = f2bf((ov[vb][rg * 4 + 2] + mrg[(qg * 32 + vb * 16 + rg * 4 + 2) * 64 + lane]) * inv);
        o.w = f2bf((ov[vb][rg * 4 + 3] + mrg[(qg * 32 + vb * 16 + rg * 4 + 3) * 64 + lane]) * inv);
        *(us4*)&ctx[(rb + qrow) * 512 + h * 64 + vb * 32 + rg * 8 + hi * 4] = o;
      }
    }
  }
}

// ---------- launch ----------
extern "C" void kernel_launch(void* const* d_in, const int* in_sizes, int n_in,
                              void* d_out, int out_size, void* d_ws, size_t ws_size,
                              hipStream_t stream) {
  (void)in_sizes; (void)n_in; (void)out_size; (void)ws_size;
  const float* Q = (const float*)d_in[0];
  const float* K = (const float*)d_in[1];
  const float* V = (const float*)d_in[2];
  const float* W_q = (const float*)d_in[3];
  const float* W_k = (const float*)d_in[4];
  const float* W_v = (const float*)d_in[5];
  const float* W_o = (const float*)d_in[6];
  const float* ln1_g = (const float*)d_in[7];
  const float* ln1_b = (const float*)d_in[8];
  const float* ln2_g = (const float*)d_in[9];
  const float* ln2_b = (const float*)d_in[10];
  const float* w1 = (const float*)d_in[11];
  const float* b1 = (const float*)d_in[12];
  const float* w2 = (const float*)d_in[13];
  const float* b2 = (const float*)d_in[14];

  char* w = (char*)d_ws;
  const size_t MB = 1u << 20;
  u16* wqkvT = (u16*)(w);                       // 1.5 MB [1536,512]
  u16* woT = (u16*)(w + 3 * MB / 2);            // 0.5 MB
  u16* w1b = (u16*)(w + 2 * MB);                // 2 MB
  u16* w2b = (u16*)(w + 4 * MB);                // 2 MB
  u16* Qn  = (u16*)(w + 6 * MB);                // 8 MB
  u16* Kb  = (u16*)(w + 14 * MB);               // 8 MB
  u16* Vb  = (u16*)(w + 22 * MB);               // 8 MB
  u16* qb  = (u16*)(w + 30 * MB);               // 8 MB
  u16* kb  = (u16*)(w + 38 * MB);               // 8 MB (row-major K)
  u16* vtb = (u16*)(w + 46 * MB);               // 8 MB ([bh*64+dv][4096] V)
  u16* ctx = (u16*)(w + 54 * MB);               // 8 MB
  float* X = (float*)(w + 62 * MB);             // 16 MB
  u16* Xn  = (u16*)(w + 6 * MB);                // reuse Qn
  u16* hb  = (u16*)(w + 14 * MB);               // reuse Kb/Vb/qb, 32 MB

  prep_weights<<<dim3(128, 6), 256, 0, stream>>>(W_q, W_k, W_v, W_o, w1, w2,
                                                 wqkvT, woT, w1b, w2b);
  ln_cast<true><<<8192, 128, 0, stream>>>(Q, ln1_g, ln1_b, Qn, K, V, Kb, Vb);
  gemm_qkv<<<dim3(64, 12), 256, 0, stream>>>(Qn, Kb, Vb, wqkvT, qb, kb, vtb);
  attn_kernel<<<dim3(16, 32), 512, 0, stream>>>(qb, kb, vtb, ctx);
  gemm_bt<2, 64, 4, 4><<<dim3(64, 8), 256, 0, stream>>>(ctx, woT, 8192, 512, 512, X, nullptr, Q);
  ln_cast<false><<<8192, 128, 0, stream>>>(X, ln2_g, ln2_b, Xn, nullptr, nullptr, nullptr, nullptr);
  gemm_bt<3, 128, 4, 2><<<dim3(64, 16), 256, 0, stream>>>(Xn, w1b, 8192, 2048, 512, hb, b1, nullptr);
  gemm_bt<4, 64, 4, 4><<<dim3(64, 8), 256, 0, stream>>>(hb, w2b, 8192, 512, 2048, (float*)d_out, b2, X);
}